// Round 16
// baseline (228.722 us; speedup 1.0000x reference)
//
#include <hip/hip_runtime.h>

// ---------------------------------------------------------------------------
// Channel_Transformer_WGCNLayer  (B=16, N=1024, C=512)  -- bf16 MFMA pipeline
// All GEMMs: C[M,Nc] = A[M,K] @ Bt[Nc,K]^T  (K contiguous on both operands)
// GEMM round-16: BK=32, 3-BUFFER DEPTH-2 PREFETCH, 3 blocks/CU.
//   m97 comparison: per-block K-step 0.3us (BK32, 3-4 blk/CU) vs our 0.73us
//   equivalent (BK64, 2 blk/CU, 1-deep) -- the untested levers are resident
//   blocks & load cover.  LDS 48KB (3buf x 8KB x 2).  Per tile t:
//   WAIT_VM(4) [t's 4 loads oldest of 8] -> BARD -> STG(t+2 -> rot buf,
//   WAR: read at t-1, drained by BARD) -> LDA/LDB/MFMA (compiler-sched).
//   Swizzle re-derived for 64B rows: slot ^= (row>>1)&3 -> 2/quad = free.
// ---------------------------------------------------------------------------

typedef __bf16 bf16x8 __attribute__((ext_vector_type(8)));
typedef float  f32x4  __attribute__((ext_vector_type(4)));

#define DEV __device__ __forceinline__

DEV float bf2f(unsigned short u) {
  union { unsigned i; float f; } x; x.i = ((unsigned)u) << 16; return x.f;
}
DEV unsigned short f2bf(float f) {           // round-to-nearest-even
  unsigned u = __float_as_uint(f);
  u += 0x7fffu + ((u >> 16) & 1u);
  return (unsigned short)(u >> 16);
}
DEV float sigmoidf_(float x) { return 1.0f / (1.0f + __expf(-x)); }

DEV float wave_sum(float v) {
#pragma unroll
  for (int o = 32; o > 0; o >>= 1) v += __shfl_xor(v, o, 64);
  return v;
}
DEV float wave_max(float v) {
#pragma unroll
  for (int o = 32; o > 0; o >>= 1) v = fmaxf(v, __shfl_xor(v, o, 64));
  return v;
}

// async global->LDS, 16B per lane; lds dest is wave-uniform (HW adds lane*16)
DEV void gload16(const unsigned short* g, unsigned short* l) {
  __builtin_amdgcn_global_load_lds(
      (const __attribute__((address_space(1))) unsigned int*)g,
      (__attribute__((address_space(3))) unsigned int*)l, 16, 0, 0);
}

// BARD: drain own LDS ops, then rendezvous (lgkmcnt(0) fused with s_barrier).
#define BARD()       asm volatile("s_waitcnt lgkmcnt(0)\n\ts_barrier" ::: "memory")
#define WAIT_VM(n)   asm volatile("s_waitcnt vmcnt(" #n ")" ::: "memory")

// --------------- fused f32 -> bf16 cast over 5 regions (1 dispatch) --------
__global__ __launch_bounds__(256) void cast5_kernel(
    const float* __restrict__ s0, unsigned short* __restrict__ d0,  // nf
    const float* __restrict__ s1, unsigned short* __restrict__ d1,  // lw
    const float* __restrict__ s2, unsigned short* __restrict__ d2,  // qw
    const float* __restrict__ s3, unsigned short* __restrict__ d3,  // kw
    const float* __restrict__ s4, unsigned short* __restrict__ d4) {// vw
  const int c0 = 2097152;            // 16*1024*512/4
  const int c1 = c0 + 65536;         // + 512*512/4
  const int c2 = c1 + 262144;        // + 1024*1024/4
  const int c3 = c2 + 262144;
  int g = blockIdx.x * 256 + threadIdx.x;   // < c3 + 262144 = 2949120
  const float* s; unsigned short* d; int i;
  if (g < c0)      { s = s0; d = d0; i = g; }
  else if (g < c1) { s = s1; d = d1; i = g - c0; }
  else if (g < c2) { s = s2; d = d2; i = g - c1; }
  else if (g < c3) { s = s3; d = d3; i = g - c2; }
  else             { s = s4; d = d4; i = g - c3; }
  float4 v = *(const float4*)(s + (size_t)i * 4);
  ushort4 o;
  o.x = f2bf(v.x); o.y = f2bf(v.y); o.z = f2bf(v.z); o.w = f2bf(v.w);
  *(ushort4*)(d + (size_t)i * 4) = o;
}

// ------------------- degree: d_is[b,n] = rsqrt(sum_m adj*sig) --------------
__global__ __launch_bounds__(256) void sigrow_kernel(const float* __restrict__ adj,
                                                     const float* __restrict__ edge,
                                                     float* __restrict__ dis) {
  __shared__ float sh[4];
  size_t row = blockIdx.x;                 // b*1024 + n
  int n = (int)(row & 1023);
  const float* ar = adj + row * 1024;
  const float* er = edge + (size_t)n * 1024;
  int c = threadIdx.x * 4;
  float4 a4 = *(const float4*)(ar + c);
  float4 e4 = *(const float4*)(er + c);
  float s = a4.x * sigmoidf_(e4.x) + a4.y * sigmoidf_(e4.y) +
            a4.z * sigmoidf_(e4.z) + a4.w * sigmoidf_(e4.w);
  s = wave_sum(s);
  if ((threadIdx.x & 63) == 0) sh[threadIdx.x >> 6] = s;
  __syncthreads();
  if (threadIdx.x == 0) {
    float t = sh[0] + sh[1] + sh[2] + sh[3];
    dis[row] = t > 0.0f ? rsqrtf(t) : 0.0f;
  }
}

// -------------- W_A_norm[b,n,m] = d[n]*adj*sig(edge)*d[m] -> bf16 ----------
__global__ __launch_bounds__(256) void wa_kernel(const float* __restrict__ adj,
                                                 const float* __restrict__ edge,
                                                 const float* __restrict__ dis,
                                                 unsigned short* __restrict__ wa) {
  size_t g = (size_t)blockIdx.x * 256 + threadIdx.x;   // group of 4 along m
  int m = (int)(g & 255) * 4;
  size_t rest = g >> 8;                                // b*1024 + n
  int n = (int)(rest & 1023);
  int b = (int)(rest >> 10);
  float4 a4 = *(const float4*)(adj + rest * 1024 + m);
  float4 e4 = *(const float4*)(edge + (size_t)n * 1024 + m);
  float dn = dis[rest];
  float4 dm = *(const float4*)(dis + (size_t)b * 1024 + m);
  ushort4 o;
  o.x = f2bf(dn * a4.x * sigmoidf_(e4.x) * dm.x);
  o.y = f2bf(dn * a4.y * sigmoidf_(e4.y) * dm.y);
  o.z = f2bf(dn * a4.z * sigmoidf_(e4.z) * dm.z);
  o.w = f2bf(dn * a4.w * sigmoidf_(e4.w) * dm.w);
  *(ushort4*)(wa + g * 4) = o;
}

// --------------------------- LayerNorm over rows ---------------------------
// NW = waves per block; block = NW*64 threads, D = NW*64*VPT.
template <int VPT, int NW, bool OUTF32>
__global__ void ln_kernel(const unsigned short* __restrict__ in,
                          const float* __restrict__ gw,
                          const float* __restrict__ gb,
                          void* __restrict__ out, int D) {
  __shared__ float sh[2 * NW];
  size_t row = blockIdx.x;
  const unsigned short* x = in + row * (size_t)D;
  int base = threadIdx.x * VPT;
  float v[VPT];
  ushort4 u = *(const ushort4*)(x + base);
  v[0] = bf2f(u.x); v[1] = bf2f(u.y); v[2] = bf2f(u.z); v[3] = bf2f(u.w);
  float s = 0.f, sq = 0.f;
#pragma unroll
  for (int i = 0; i < VPT; i++) { s += v[i]; sq += v[i] * v[i]; }
  s = wave_sum(s); sq = wave_sum(sq);
  int wv = threadIdx.x >> 6;
  if ((threadIdx.x & 63) == 0) { sh[wv] = s; sh[NW + wv] = sq; }
  __syncthreads();
  s = 0.f; sq = 0.f;
#pragma unroll
  for (int i = 0; i < NW; i++) { s += sh[i]; sq += sh[NW + i]; }
  float mean = s / D;
  float var = sq / D - mean * mean;
  float rs = rsqrtf(fmaxf(var, 0.0f) + 1e-5f);
#pragma unroll
  for (int i = 0; i < VPT; i++) {
    float y = (v[i] - mean) * rs * gw[base + i] + gb[base + i];
    if (OUTF32) ((float*)out)[row * D + base + i] = y;
    else        ((unsigned short*)out)[row * D + base + i] = f2bf(y);
  }
}

// ------------- softmax over rows of 512 (sums 2 split-K partials) ----------
__global__ __launch_bounds__(256) void softmax_kernel(const float* __restrict__ in,
                                                      const float* __restrict__ in2,
                                                      unsigned short* __restrict__ out) {
  __shared__ float sh[4];
  size_t row = blockIdx.x;
  const float* x = in + row * 512;
  const float* x2 = in2 + row * 512;
  float2 u = *(const float2*)(x + threadIdx.x * 2);
  float2 u2 = *(const float2*)(x2 + threadIdx.x * 2);
  float a = (u.x + u2.x) * 0.03125f, b = (u.y + u2.y) * 0.03125f;  // 1024^-0.5
  float m = wave_max(fmaxf(a, b));
  int wid = threadIdx.x >> 6;
  if ((threadIdx.x & 63) == 0) sh[wid] = m;
  __syncthreads();
  m = fmaxf(fmaxf(sh[0], sh[1]), fmaxf(sh[2], sh[3]));
  __syncthreads();
  float e0 = __expf(a - m), e1 = __expf(b - m);
  float s = wave_sum(e0 + e1);
  if ((threadIdx.x & 63) == 0) sh[wid] = s;
  __syncthreads();
  s = sh[0] + sh[1] + sh[2] + sh[3];
  float inv = 1.0f / s;
  ushort2 o; o.x = f2bf(e0 * inv); o.y = f2bf(e1 * inv);
  *(ushort2*)(out + row * 512 + threadIdx.x * 2) = o;
}

// ===== 128x128 bf16 MFMA GEMM, BK=32, 3-buffer depth-2, 3 blocks/CU ========
// 256 thr = 4 waves (2M x 2N), wave tile 64x64, acc[4][4].
// LDS: As[3][128*32] + Bs[3][128*32] = 48 KiB -> 3 blocks/CU.
// Per tile: 2 gloads A + 2 gloads B per wave (4/wave); 8 ds_read_b128;
// 16 MFMA.  Swizzle (64B rows, 4 slots): slot ^= (row>>1)&3 -> 16 lanes hit
// all 8 bank-quads (2-way = free, m136).  Applied on global src + ds_read.
// Sync per tile t (read buf p0, stage t+2 -> buf p2, rotate):
//   WAIT_VM(4|0)  -- t's 4 loads are the oldest of 8 outstanding (in-order)
//   BARD          -- cross-wave RAW for buf p0 + read-drain for buf p2 (WAR:
//                    p2 was the read buffer at t-1)
//   STG(p2, t+2); LDA(p0); LDB(p0); 16 MFMA  -- compiler-scheduled
#define MFMA16(d, s0, s1) d = __builtin_amdgcn_mfma_f32_16x16x32_bf16(s0, s1, d, 0, 0, 0)

#define STG(bo, kt) do { \
  gload16(gA + (size_t)(kt) * 32, As + (bo) + ldst); \
  gload16(gA + rowskip + (size_t)(kt) * 32, As + (bo) + 2048 + ldst); \
  gload16(gB + (size_t)(kt) * 32, Bs + (bo) + ldst); \
  gload16(gB + rowskip + (size_t)(kt) * 32, Bs + (bo) + 2048 + ldst); \
} while (0)

#define LDA(bo) do { \
  _Pragma("unroll") for (int mf = 0; mf < 4; mf++) \
    a[mf] = *(const bf16x8*)&As[(bo) + (wr * 64 + mf * 16 + l15) * 32 + xsw]; \
} while (0)
#define LDB(bo) do { \
  _Pragma("unroll") for (int nf = 0; nf < 4; nf++) \
    bb[nf] = *(const bf16x8*)&Bs[(bo) + (wc * 64 + nf * 16 + l15) * 32 + xsw]; \
} while (0)

#define MMALL() do { \
  _Pragma("unroll") for (int mf = 0; mf < 4; mf++) \
  _Pragma("unroll") for (int nf = 0; nf < 4; nf++) \
    MFMA16(acc[mf][nf], a[mf], bb[nf]); \
} while (0)

template <int BIAS /*0 none,1 row,2 col*/, bool LEAKY, bool RESID,
          bool OUTF32, bool SPLIT, bool SPLITK>
__global__ __launch_bounds__(256) void gemm128(
    const unsigned short* __restrict__ A, size_t sA,
    const unsigned short* __restrict__ Bt, size_t sB,
    const float* __restrict__ bias, const float* __restrict__ bias2,
    const unsigned short* __restrict__ resid,
    void* __restrict__ out, void* __restrict__ out2,
    int M, int NcS, int K, int Kst, int lgx, int lgy, int xh) {
  __shared__ unsigned short As[3 * 4096];    // [buf][128 rows][32] swizzled
  __shared__ unsigned short Bs[3 * 4096];
  // ---- XCD-chunked bijective swizzle (grid divisible by 8) ----
  const int qc = gridDim.x >> 3;
  const int dd = blockIdx.x;
  const int lb = (dd & 7) * qc + (dd >> 3);
  const int x = lb & ((1 << lgx) - 1);
  const int y = (lb >> lgx) & ((1 << lgy) - 1);
  const int b = (lb >> (lgx + lgy)) & 15;
  const int sk = SPLITK ? (lb >> (lgx + lgy + 4)) : 0;

  const int tid = threadIdx.x;
  const int wid = tid >> 6, lane = tid & 63;
  const int wr = wid >> 1, wc = wid & 1;        // 2 x 2 wave grid
  const int l15 = lane & 15, l4 = lane >> 4;
  const int tM = y * 128, tN = x * 128;
  const size_t Kr = (size_t)Kst;

  // staging: round h covers rows h*64; lane l -> row wid*16+(l>>2),
  // 16B slot (l&3) pre-swizzled on the GLOBAL src: slot ^= (row>>1)&3,
  // where (row>>1)&3 == (lane>>3)&3 for this mapping.
  const int srow = wid * 16 + (lane >> 2);
  const int scol = ((lane & 3) ^ ((lane >> 3) & 3)) * 8;
  const int koff = sk * K;                      // split-K column offset
  const unsigned short* gA = A + sA * b + (size_t)(tM + srow) * Kr + scol + koff;
  const unsigned short* gB = Bt + sB * b + (size_t)(tN + srow) * Kr + scol + koff;
  const size_t rowskip = (size_t)64 * Kr;       // 2nd staging round (+64 rows)
  const int ldst = wid * 512;                   // wave-uniform LDS base (shorts)

  // ds_read: addr = row*32 + ((l4 ^ ((row>>1)&3))*8); (row>>1)&3 == (l15>>1)&3
  const int xsw = ((l4 ^ ((l15 >> 1) & 3)) * 8);
  f32x4 acc[4][4] = {};
  bf16x8 a[4], bb[4];

  const int nt = K >> 5;                        // 16 (K=512) or 32 (K=1024)
  // prologue: stage tiles 0 and 1 (oldest-first)
  STG(0, 0);                                    // tile 0 -> buf 0
  STG(4096, 1);                                 // tile 1 -> buf 1
  int p0 = 0, p1 = 4096, p2 = 8192;             // rotating buffer offsets

  for (int kt = 0; kt < nt; ++kt) {
    if (kt == nt - 1) { WAIT_VM(0); } else { WAIT_VM(4); }
    BARD();
    if (kt < nt - 2) STG(p2, kt + 2);
    LDA(p0); LDB(p0);
    MMALL();
    int tmp = p0; p0 = p1; p1 = p2; p2 = tmp;   // rotate
  }

  // ------------------------------ epilogue ---------------------------------
  const float* bia = bias;
  void* o = out;
  if (SPLIT && x >= xh) { bia = bias2; o = out2; }
  if (SPLITK && sk) o = out2;
  const size_t ob = (size_t)M * NcS * b;
#pragma unroll
  for (int mf = 0; mf < 4; mf++)
#pragma unroll
    for (int nf = 0; nf < 4; nf++) {
      const int cg = tN + wc * 64 + nf * 16 + l15;
      const int rbase = tM + wr * 64 + mf * 16 + l4 * 4;
#pragma unroll
      for (int r = 0; r < 4; r++) {
        const int rg = rbase + r;
        float v = acc[mf][nf][r];
        if (BIAS == 1) v += bia[rg];
        if (BIAS == 2) v += bia[cg];
        if (LEAKY) v = v > 0.0f ? v : 0.01f * v;
        const size_t idx = ob + (size_t)rg * NcS + cg;
        if (RESID) v += bf2f(resid[idx]);
        if (OUTF32) ((float*)o)[idx] = v;
        else        ((unsigned short*)o)[idx] = f2bf(v);
      }
    }
}

// ---------------------------------------------------------------------------
extern "C" void kernel_launch(void* const* d_in, const int* in_sizes, int n_in,
                              void* d_out, int out_size, void* d_ws, size_t ws_size,
                              hipStream_t stream) {
  const float* node_feats = (const float*)d_in[0];   // [16,1024,512]
  const float* adj        = (const float*)d_in[1];   // [16,1024,1024]
  const float* linear_w   = (const float*)d_in[2];   // [512,512]
  const float* linear_b   = (const float*)d_in[3];   // [512]
  const float* q_w        = (const float*)d_in[4];   // [1024,1024]
  const float* q_b        = (const float*)d_in[5];
  const float* k_w        = (const float*)d_in[6];
  const float* k_b        = (const float*)d_in[7];
  const float* v_w        = (const float*)d_in[8];
  const float* v_b        = (const float*)d_in[9];
  const float* n1w        = (const float*)d_in[10];  // [1024]
  const float* n1b        = (const float*)d_in[11];
  const float* n2w        = (const float*)d_in[12];  // [512]
  const float* n2b        = (const float*)d_in[13];
  const float* edge       = (const float*)d_in[14];  // [1024,1024]
  float* out = (float*)d_out;

  const int B = 16, N = 1024, C = 512;
  const size_t MiB = 1u << 20;
  char* w = (char*)d_ws;
  // lifetime-aliased workspace layout (total ~119.1 MiB)
  unsigned short* nf_bf   = (unsigned short*)(w);             // 16 MiB [dies after G1]
  unsigned short* Xt_bf   = (unsigned short*)(w + 16 * MiB);  // 16 MiB [dies after LN1]
  float*          att_raw = (float*)(w);                      // 16 MiB (reuses nf)
  float*          att_raw2= (float*)(w + 16 * MiB);           // 16 MiB (reuses Xt)
  unsigned short* WA_bf   = (unsigned short*)(w);             // 32 MiB (after softmax)
  unsigned short* Txln    = (unsigned short*)(w + 32 * MiB);  // 16 MiB
  unsigned short* q_bf    = (unsigned short*)(w + 48 * MiB);  // 16 MiB [dies after att]
  unsigned short* X3_bf   = (unsigned short*)(w + 48 * MiB);  // 16 MiB (reuses q)
  unsigned short* k_bf    = (unsigned short*)(w + 64 * MiB);  // 16 MiB [dies after att]
  unsigned short* att_bf  = (unsigned short*)(w + 64 * MiB);  //  8 MiB (reuses k)
  unsigned short* vt_bf   = (unsigned short*)(w + 80 * MiB);  // 16 MiB
  unsigned short* Tx2_bf  = (unsigned short*)(w + 96 * MiB);  // 16 MiB
  unsigned short* lw_bf   = (unsigned short*)(w + 112 * MiB); // 0.5 MiB
  unsigned short* qw_bf   = (unsigned short*)(w + 113 * MiB); // 2 MiB \ adjacent: one
  unsigned short* kw_bf   = (unsigned short*)(w + 115 * MiB); // 2 MiB / [2048,1024] matrix
  unsigned short* vw_bf   = (unsigned short*)(w + 117 * MiB); // 2 MiB
  float*          dis     = (float*)(w + 119 * MiB);          // 64 KiB

  // all f32->bf16 casts in ONE dispatch (nf, lw, qw, kw, vw)
  cast5_kernel<<<(2949120 + 255) / 256, 256, 0, stream>>>(
      node_feats, nf_bf, linear_w, lw_bf, q_w, qw_bf, k_w, kw_bf, v_w, vw_bf);

  // degree normalization factors
  sigrow_kernel<<<B * N, 256, 0, stream>>>(adj, edge, dis);

  // G1: Xt[b,o,n] = leaky(lw @ nf^T + lb[o])  M=512,Nc=1024,K=512  grid 8x4x16
  gemm128<1, true, false, false, false, false><<<512, 256, 0, stream>>>(
      lw_bf, 0, nf_bf, (size_t)N * C, linear_b, nullptr, nullptr,
      Xt_bf, nullptr, C, N, C, C, 3, 2, 999);

  // LN1 over n (D=1024) -> Txln bf16   (256 thr x VPT4)
  ln_kernel<4, 4, false><<<B * C, 256, 0, stream>>>(Xt_bf, n1w, n1b, Txln, N);

  // fused q|k: Txln @ [qw;kw]^T + [qb;kb]  M=512,Nc=2048,K=1024  grid 16x4x16
  // x<8 -> q, x>=8 -> k (out2/bias2 pre-shifted by -1024 cols)
  gemm128<2, false, false, false, true, false><<<1024, 256, 0, stream>>>(
      Txln, (size_t)C * N, qw_bf, 0, q_b, k_b - 1024, nullptr,
      q_bf, (void*)(k_bf - 1024), C, N, N, N, 4, 2, 8);

  // v^T: vt[b,g,x] = leaky(v_w @ Txln^T + v_b[g])  M=1024,Nc=512,K=1024  grid 4x8x16
  gemm128<1, true, false, false, false, false><<<512, 256, 0, stream>>>(
      vw_bf, 0, Txln, (size_t)C * N, v_b, nullptr, nullptr,
      vt_bf, nullptr, N, C, N, N, 2, 3, 999);

  // att partials: q @ k^T  M=512,Nc=512, K=1024 split 2x512  grid 4x4x16x2
  gemm128<0, false, false, true, false, true><<<512, 256, 0, stream>>>(
      q_bf, (size_t)C * N, k_bf, (size_t)C * N, nullptr, nullptr, nullptr,
      att_raw, att_raw2, C, C, 512, N, 2, 2, 999);

  // softmax((p0+p1) * 1/32) -> att_bf
  softmax_kernel<<<B * C, 256, 0, stream>>>(att_raw, att_raw2, att_bf);

  // W_A normalized bf16 (overwrites bytes [0,32MiB): partials dead)
  wa_kernel<<<B * N * N / 4 / 256, 256, 0, stream>>>(adj, edge, dis, WA_bf);

  // Tx2[b,x,h] = Txln + att @ v   M=512,Nc=1024,K=512  grid 8x4x16
  gemm128<0, false, true, false, false, false><<<512, 256, 0, stream>>>(
      att_bf, (size_t)C * C, vt_bf, (size_t)N * C, nullptr, nullptr, Txln,
      Tx2_bf, nullptr, C, N, C, C, 3, 2, 999);

  // X3[b,n,o] = W_A @ X2   M=1024,Nc=512,K=1024  grid 4x8x16
  gemm128<0, false, false, false, false, false><<<512, 256, 0, stream>>>(
      WA_bf, (size_t)N * N, Tx2_bf, (size_t)C * N, nullptr, nullptr, nullptr,
      X3_bf, nullptr, N, C, N, N, 2, 3, 999);

  // final LN over o (D=512) -> f32 out   (128 thr x VPT4, 8B/lane loads)
  ln_kernel<4, 2, true><<<B * N, 128, 0, stream>>>(X3_bf, n2w, n2b, out, C);
}

// Round 17
// 201.438 us; speedup vs baseline: 1.1354x; 1.1354x over previous
//
#include <hip/hip_runtime.h>

// ---------------------------------------------------------------------------
// Channel_Transformer_WGCNLayer  (B=16, N=1024, C=512)  -- bf16 MFMA pipeline
// All GEMMs: C[M,Nc] = A[M,K] @ Bt[Nc,K]^T  (K contiguous on both operands)
// FINAL (r15 revert): gemm128 = 128x128, BK=64, 4 waves, 2 blocks/CU,
//   1 barrier/K-tile (WAIT_VM(0) -> BARD -> STG(t+1) -> reads+MFMAs),
//   XOR-swizzled LDS (0 bank conflicts, PMC-verified), XCD-chunked bijective
//   block swizzle, fused q|k dispatch, att split-K=2, fused cast, vectorized
//   LN.  r16's BK=32/3-buffer regressed (228.7 vs 202.5): time tracks
//   interval-count x fixed rendezvous cost; r15 config is the measured
//   optimum across 10 structural variants (r6-r16).
// ---------------------------------------------------------------------------

typedef __bf16 bf16x8 __attribute__((ext_vector_type(8)));
typedef float  f32x4  __attribute__((ext_vector_type(4)));

#define DEV __device__ __forceinline__

DEV float bf2f(unsigned short u) {
  union { unsigned i; float f; } x; x.i = ((unsigned)u) << 16; return x.f;
}
DEV unsigned short f2bf(float f) {           // round-to-nearest-even
  unsigned u = __float_as_uint(f);
  u += 0x7fffu + ((u >> 16) & 1u);
  return (unsigned short)(u >> 16);
}
DEV float sigmoidf_(float x) { return 1.0f / (1.0f + __expf(-x)); }

DEV float wave_sum(float v) {
#pragma unroll
  for (int o = 32; o > 0; o >>= 1) v += __shfl_xor(v, o, 64);
  return v;
}
DEV float wave_max(float v) {
#pragma unroll
  for (int o = 32; o > 0; o >>= 1) v = fmaxf(v, __shfl_xor(v, o, 64));
  return v;
}

// async global->LDS, 16B per lane; lds dest is wave-uniform (HW adds lane*16)
DEV void gload16(const unsigned short* g, unsigned short* l) {
  __builtin_amdgcn_global_load_lds(
      (const __attribute__((address_space(1))) unsigned int*)g,
      (__attribute__((address_space(3))) unsigned int*)l, 16, 0, 0);
}

// BARD: drain own LDS ops, then rendezvous (lgkmcnt(0) fused with s_barrier).
#define BARD()       asm volatile("s_waitcnt lgkmcnt(0)\n\ts_barrier" ::: "memory")
#define WAIT_VM(n)   asm volatile("s_waitcnt vmcnt(" #n ")" ::: "memory")

// --------------- fused f32 -> bf16 cast over 5 regions (1 dispatch) --------
__global__ __launch_bounds__(256) void cast5_kernel(
    const float* __restrict__ s0, unsigned short* __restrict__ d0,  // nf
    const float* __restrict__ s1, unsigned short* __restrict__ d1,  // lw
    const float* __restrict__ s2, unsigned short* __restrict__ d2,  // qw
    const float* __restrict__ s3, unsigned short* __restrict__ d3,  // kw
    const float* __restrict__ s4, unsigned short* __restrict__ d4) {// vw
  // region sizes in float4-quads
  const int c0 = 2097152;            // 16*1024*512/4
  const int c1 = c0 + 65536;         // + 512*512/4
  const int c2 = c1 + 262144;        // + 1024*1024/4
  const int c3 = c2 + 262144;
  int g = blockIdx.x * 256 + threadIdx.x;   // < c3 + 262144 = 2949120
  const float* s; unsigned short* d; int i;
  if (g < c0)      { s = s0; d = d0; i = g; }
  else if (g < c1) { s = s1; d = d1; i = g - c0; }
  else if (g < c2) { s = s2; d = d2; i = g - c1; }
  else if (g < c3) { s = s3; d = d3; i = g - c2; }
  else             { s = s4; d = d4; i = g - c3; }
  float4 v = *(const float4*)(s + (size_t)i * 4);
  ushort4 o;
  o.x = f2bf(v.x); o.y = f2bf(v.y); o.z = f2bf(v.z); o.w = f2bf(v.w);
  *(ushort4*)(d + (size_t)i * 4) = o;
}

// ------------------- degree: d_is[b,n] = rsqrt(sum_m adj*sig) --------------
__global__ __launch_bounds__(256) void sigrow_kernel(const float* __restrict__ adj,
                                                     const float* __restrict__ edge,
                                                     float* __restrict__ dis) {
  __shared__ float sh[4];
  size_t row = blockIdx.x;                 // b*1024 + n
  int n = (int)(row & 1023);
  const float* ar = adj + row * 1024;
  const float* er = edge + (size_t)n * 1024;
  int c = threadIdx.x * 4;
  float4 a4 = *(const float4*)(ar + c);
  float4 e4 = *(const float4*)(er + c);
  float s = a4.x * sigmoidf_(e4.x) + a4.y * sigmoidf_(e4.y) +
            a4.z * sigmoidf_(e4.z) + a4.w * sigmoidf_(e4.w);
  s = wave_sum(s);
  if ((threadIdx.x & 63) == 0) sh[threadIdx.x >> 6] = s;
  __syncthreads();
  if (threadIdx.x == 0) {
    float t = sh[0] + sh[1] + sh[2] + sh[3];
    dis[row] = t > 0.0f ? rsqrtf(t) : 0.0f;
  }
}

// -------------- W_A_norm[b,n,m] = d[n]*adj*sig(edge)*d[m] -> bf16 ----------
__global__ __launch_bounds__(256) void wa_kernel(const float* __restrict__ adj,
                                                 const float* __restrict__ edge,
                                                 const float* __restrict__ dis,
                                                 unsigned short* __restrict__ wa) {
  size_t g = (size_t)blockIdx.x * 256 + threadIdx.x;   // group of 4 along m
  int m = (int)(g & 255) * 4;
  size_t rest = g >> 8;                                // b*1024 + n
  int n = (int)(rest & 1023);
  int b = (int)(rest >> 10);
  float4 a4 = *(const float4*)(adj + rest * 1024 + m);
  float4 e4 = *(const float4*)(edge + (size_t)n * 1024 + m);
  float dn = dis[rest];
  float4 dm = *(const float4*)(dis + (size_t)b * 1024 + m);
  ushort4 o;
  o.x = f2bf(dn * a4.x * sigmoidf_(e4.x) * dm.x);
  o.y = f2bf(dn * a4.y * sigmoidf_(e4.y) * dm.y);
  o.z = f2bf(dn * a4.z * sigmoidf_(e4.z) * dm.z);
  o.w = f2bf(dn * a4.w * sigmoidf_(e4.w) * dm.w);
  *(ushort4*)(wa + g * 4) = o;
}

// --------------------------- LayerNorm over rows ---------------------------
// NW = waves per block; block = NW*64 threads, D = NW*64*VPT.
template <int VPT, int NW, bool OUTF32>
__global__ void ln_kernel(const unsigned short* __restrict__ in,
                          const float* __restrict__ gw,
                          const float* __restrict__ gb,
                          void* __restrict__ out, int D) {
  __shared__ float sh[2 * NW];
  size_t row = blockIdx.x;
  const unsigned short* x = in + row * (size_t)D;
  int base = threadIdx.x * VPT;
  float v[VPT];
  ushort4 u = *(const ushort4*)(x + base);
  v[0] = bf2f(u.x); v[1] = bf2f(u.y); v[2] = bf2f(u.z); v[3] = bf2f(u.w);
  float s = 0.f, sq = 0.f;
#pragma unroll
  for (int i = 0; i < VPT; i++) { s += v[i]; sq += v[i] * v[i]; }
  s = wave_sum(s); sq = wave_sum(sq);
  int wv = threadIdx.x >> 6;
  if ((threadIdx.x & 63) == 0) { sh[wv] = s; sh[NW + wv] = sq; }
  __syncthreads();
  s = 0.f; sq = 0.f;
#pragma unroll
  for (int i = 0; i < NW; i++) { s += sh[i]; sq += sh[NW + i]; }
  float mean = s / D;
  float var = sq / D - mean * mean;
  float rs = rsqrtf(fmaxf(var, 0.0f) + 1e-5f);
#pragma unroll
  for (int i = 0; i < VPT; i++) {
    float y = (v[i] - mean) * rs * gw[base + i] + gb[base + i];
    if (OUTF32) ((float*)out)[row * D + base + i] = y;
    else        ((unsigned short*)out)[row * D + base + i] = f2bf(y);
  }
}

// ------------- softmax over rows of 512 (sums 2 split-K partials) ----------
__global__ __launch_bounds__(256) void softmax_kernel(const float* __restrict__ in,
                                                      const float* __restrict__ in2,
                                                      unsigned short* __restrict__ out) {
  __shared__ float sh[4];
  size_t row = blockIdx.x;
  const float* x = in + row * 512;
  const float* x2 = in2 + row * 512;
  float2 u = *(const float2*)(x + threadIdx.x * 2);
  float2 u2 = *(const float2*)(x2 + threadIdx.x * 2);
  float a = (u.x + u2.x) * 0.03125f, b = (u.y + u2.y) * 0.03125f;  // 1024^-0.5
  float m = wave_max(fmaxf(a, b));
  int wid = threadIdx.x >> 6;
  if ((threadIdx.x & 63) == 0) sh[wid] = m;
  __syncthreads();
  m = fmaxf(fmaxf(sh[0], sh[1]), fmaxf(sh[2], sh[3]));
  __syncthreads();
  float e0 = __expf(a - m), e1 = __expf(b - m);
  float s = wave_sum(e0 + e1);
  if ((threadIdx.x & 63) == 0) sh[wid] = s;
  __syncthreads();
  s = sh[0] + sh[1] + sh[2] + sh[3];
  float inv = 1.0f / s;
  ushort2 o; o.x = f2bf(e0 * inv); o.y = f2bf(e1 * inv);
  *(ushort2*)(out + row * 512 + threadIdx.x * 2) = o;
}

// ======== 1-barrier-per-K-tile 128x128 bf16 MFMA GEMM, 2 blocks/CU =========
// 256 thr = 4 waves (2M x 2N), wave tile 64x64, acc[4][4], BK=64.
// LDS: [2buf][128 rows][64] per operand = 64 KiB total -> 2 blocks/CU.
// Interval t (P=t&1):
//   WAIT_VM(0)  -- own tile-t loads landed (only tile t in flight here)
//   BARD        -- ALL waves' tile-t loads landed + all reads of P^1 drained
//   STG(t+1 -> P^1)  -- WAR-safe per BARD's fused lgkmcnt(0)
//   LDA,LDB,MFMAs    -- compiler-scheduled (fine-grained lgkmcnt interleave)
#define MFMA16(d, s0, s1) d = __builtin_amdgcn_mfma_f32_16x16x32_bf16(s0, s1, d, 0, 0, 0)

#define STGA(bi, kt) do { \
  _Pragma("unroll") for (int h = 0; h < 4; h++) \
    gload16(gA + (size_t)(h * 32) * Kr + (size_t)(kt) * 64, \
            As + (bi) * 8192 + h * 2048 + ldst); \
} while (0)
#define STGB(bi, kt) do { \
  _Pragma("unroll") for (int h = 0; h < 4; h++) \
    gload16(gB + (size_t)(h * 32) * Kr + (size_t)(kt) * 64, \
            Bs + (bi) * 8192 + h * 2048 + ldst); \
} while (0)

#define LDA(bi) do { \
  _Pragma("unroll") for (int mf = 0; mf < 4; mf++) { \
    a[mf][0] = *(const bf16x8*)&As[(bi) * 8192 + arow + mf * 1024 + xs0]; \
    a[mf][1] = *(const bf16x8*)&As[(bi) * 8192 + arow + mf * 1024 + xs1]; \
  } } while (0)
#define LDB(bi) do { \
  _Pragma("unroll") for (int nf = 0; nf < 4; nf++) { \
    bb[nf][0] = *(const bf16x8*)&Bs[(bi) * 8192 + brow + nf * 1024 + xs0]; \
    bb[nf][1] = *(const bf16x8*)&Bs[(bi) * 8192 + brow + nf * 1024 + xs1]; \
  } } while (0)

#define MMALL() do { \
  _Pragma("unroll") for (int mf = 0; mf < 4; mf++) \
  _Pragma("unroll") for (int nf = 0; nf < 4; nf++) { \
    MFMA16(acc[mf][nf], a[mf][0], bb[nf][0]); \
    MFMA16(acc[mf][nf], a[mf][1], bb[nf][1]); \
  } } while (0)

#define TILE1(P, kt, SG) do { \
  WAIT_VM(0); \
  BARD(); \
  if (SG) { STGA((P) ^ 1, (kt) + 1); STGB((P) ^ 1, (kt) + 1); } \
  LDA(P); LDB(P); \
  MMALL(); \
} while (0)

template <int BIAS /*0 none,1 row,2 col*/, bool LEAKY, bool RESID,
          bool OUTF32, bool SPLIT, bool SPLITK>
__global__ __launch_bounds__(256, 2) void gemm128(
    const unsigned short* __restrict__ A, size_t sA,
    const unsigned short* __restrict__ Bt, size_t sB,
    const float* __restrict__ bias, const float* __restrict__ bias2,
    const unsigned short* __restrict__ resid,
    void* __restrict__ out, void* __restrict__ out2,
    int M, int NcS, int K, int Kst, int lgx, int lgy, int xh) {
  __shared__ unsigned short As[2 * 8192];    // [buf][128 rows][64] swizzled
  __shared__ unsigned short Bs[2 * 8192];
  // ---- XCD-chunked bijective swizzle (grid divisible by 8) ----
  const int qc = gridDim.x >> 3;
  const int dd = blockIdx.x;
  const int lb = (dd & 7) * qc + (dd >> 3);
  const int x = lb & ((1 << lgx) - 1);
  const int y = (lb >> lgx) & ((1 << lgy) - 1);
  const int b = (lb >> (lgx + lgy)) & 15;
  const int sk = SPLITK ? (lb >> (lgx + lgy + 4)) : 0;

  const int tid = threadIdx.x;
  const int wid = tid >> 6, lane = tid & 63;
  const int wr = wid >> 1, wc = wid & 1;        // 2 x 2 wave grid
  const int l15 = lane & 15, l4 = lane >> 4;
  const int tM = y * 128, tN = x * 128;
  const size_t Kr = (size_t)Kst;

  // staging: per round, 4 waves cover 32 rows: lane l -> row wid*8+(l>>3),
  // 16B slot (l&7); global src col pre-swizzled by ^(row&7) (involution).
  const int srow = wid * 8 + (lane >> 3);
  const int scol = ((lane & 7) ^ ((lane >> 3) & 7)) * 8;
  const int koff = sk * K;                      // split-K column offset
  const unsigned short* gA = A + sA * b + (size_t)(tM + srow) * Kr + scol + koff;
  const unsigned short* gB = Bt + sB * b + (size_t)(tN + srow) * Kr + scol + koff;
  const int ldst = wid * 512;                   // wave-uniform LDS base (shorts)

  // ds_read lane bases: addr = row*64 + ((slot ^ (row&7))*8); row&7 == lane&7
  const int xs0 = ((0 * 4 + l4) ^ (lane & 7)) * 8;   // kk=0
  const int xs1 = ((1 * 4 + l4) ^ (lane & 7)) * 8;   // kk=1
  const int arow = (wr * 64 + l15) * 64;             // + mf*1024
  const int brow = (wc * 64 + l15) * 64;             // + nf*1024

  f32x4 acc[4][4] = {};
  bf16x8 a[4][2], bb[4][2];

  const int nt = K >> 6;                        // 8 (K=512) or 16 (K=1024)
  // prologue: stage tile 0 (tiles 1..nt-1 staged in-loop, 1 ahead)
  STGA(0, 0); STGB(0, 0);

  for (int kt = 0; kt < nt; ++kt)
    TILE1(kt & 1, kt, kt < nt - 1);

  // ------------------------------ epilogue ---------------------------------
  const float* bia = bias;
  void* o = out;
  if (SPLIT && x >= xh) { bia = bias2; o = out2; }
  if (SPLITK && sk) o = out2;
  const size_t ob = (size_t)M * NcS * b;
#pragma unroll
  for (int mf = 0; mf < 4; mf++)
#pragma unroll
    for (int nf = 0; nf < 4; nf++) {
      const int cg = tN + wc * 64 + nf * 16 + l15;
      const int rbase = tM + wr * 64 + mf * 16 + l4 * 4;
#pragma unroll
      for (int r = 0; r < 4; r++) {
        const int rg = rbase + r;
        float v = acc[mf][nf][r];
        if (BIAS == 1) v += bia[rg];
        if (BIAS == 2) v += bia[cg];
        if (LEAKY) v = v > 0.0f ? v : 0.01f * v;
        const size_t idx = ob + (size_t)rg * NcS + cg;
        if (RESID) v += bf2f(resid[idx]);
        if (OUTF32) ((float*)o)[idx] = v;
        else        ((unsigned short*)o)[idx] = f2bf(v);
      }
    }
}

// ---------------------------------------------------------------------------
extern "C" void kernel_launch(void* const* d_in, const int* in_sizes, int n_in,
                              void* d_out, int out_size, void* d_ws, size_t ws_size,
                              hipStream_t stream) {
  const float* node_feats = (const float*)d_in[0];   // [16,1024,512]
  const float* adj        = (const float*)d_in[1];   // [16,1024,1024]
  const float* linear_w   = (const float*)d_in[2];   // [512,512]
  const float* linear_b   = (const float*)d_in[3];   // [512]
  const float* q_w        = (const float*)d_in[4];   // [1024,1024]
  const float* q_b        = (const float*)d_in[5];
  const float* k_w        = (const float*)d_in[6];
  const float* k_b        = (const float*)d_in[7];
  const float* v_w        = (const float*)d_in[8];
  const float* v_b        = (const float*)d_in[9];
  const float* n1w        = (const float*)d_in[10];  // [1024]
  const float* n1b        = (const float*)d_in[11];
  const float* n2w        = (const float*)d_in[12];  // [512]
  const float* n2b        = (const float*)d_in[13];
  const float* edge       = (const float*)d_in[14];  // [1024,1024]
  float* out = (float*)d_out;

  const int B = 16, N = 1024, C = 512;
  const size_t MiB = 1u << 20;
  char* w = (char*)d_ws;
  // lifetime-aliased workspace layout (total ~119.1 MiB)
  unsigned short* nf_bf   = (unsigned short*)(w);             // 16 MiB [dies after G1]
  unsigned short* Xt_bf   = (unsigned short*)(w + 16 * MiB);  // 16 MiB [dies after LN1]
  float*          att_raw = (float*)(w);                      // 16 MiB (reuses nf)
  float*          att_raw2= (float*)(w + 16 * MiB);           // 16 MiB (reuses Xt)
  unsigned short* WA_bf   = (unsigned short*)(w);             // 32 MiB (after softmax)
  unsigned short* Txln    = (unsigned short*)(w + 32 * MiB);  // 16 MiB
  unsigned short* q_bf    = (unsigned short*)(w + 48 * MiB);  // 16 MiB [dies after att]
  unsigned short* X3_bf   = (unsigned short*)(w + 48 * MiB);  // 16 MiB (reuses q)
  unsigned short* k_bf    = (unsigned short*)(w + 64 * MiB);  // 16 MiB [dies after att]
  unsigned short* att_bf  = (unsigned short*)(w + 64 * MiB);  //  8 MiB (reuses k)
  unsigned short* vt_bf   = (unsigned short*)(w + 80 * MiB);  // 16 MiB
  unsigned short* Tx2_bf  = (unsigned short*)(w + 96 * MiB);  // 16 MiB
  unsigned short* lw_bf   = (unsigned short*)(w + 112 * MiB); // 0.5 MiB
  unsigned short* qw_bf   = (unsigned short*)(w + 113 * MiB); // 2 MiB \ adjacent: one
  unsigned short* kw_bf   = (unsigned short*)(w + 115 * MiB); // 2 MiB / [2048,1024] matrix
  unsigned short* vw_bf   = (unsigned short*)(w + 117 * MiB); // 2 MiB
  float*          dis     = (float*)(w + 119 * MiB);          // 64 KiB

  // all f32->bf16 casts in ONE dispatch (nf, lw, qw, kw, vw)
  cast5_kernel<<<(2949120 + 255) / 256, 256, 0, stream>>>(
      node_feats, nf_bf, linear_w, lw_bf, q_w, qw_bf, k_w, kw_bf, v_w, vw_bf);

  // degree normalization factors
  sigrow_kernel<<<B * N, 256, 0, stream>>>(adj, edge, dis);

  // G1: Xt[b,o,n] = leaky(lw @ nf^T + lb[o])  M=512,Nc=1024,K=512  grid 8x4x16
  gemm128<1, true, false, false, false, false><<<512, 256, 0, stream>>>(
      lw_bf, 0, nf_bf, (size_t)N * C, linear_b, nullptr, nullptr,
      Xt_bf, nullptr, C, N, C, C, 3, 2, 999);

  // LN1 over n (D=1024) -> Txln bf16   (256 thr x VPT4)
  ln_kernel<4, 4, false><<<B * C, 256, 0, stream>>>(Xt_bf, n1w, n1b, Txln, N);

  // fused q|k: Txln @ [qw;kw]^T + [qb;kb]  M=512,Nc=2048,K=1024  grid 16x4x16
  // x<8 -> q, x>=8 -> k (out2/bias2 pre-shifted by -1024 cols)
  gemm128<2, false, false, false, true, false><<<1024, 256, 0, stream>>>(
      Txln, (size_t)C * N, qw_bf, 0, q_b, k_b - 1024, nullptr,
      q_bf, (void*)(k_bf - 1024), C, N, N, N, 4, 2, 8);

  // v^T: vt[b,g,x] = leaky(v_w @ Txln^T + v_b[g])  M=1024,Nc=512,K=1024  grid 4x8x16
  gemm128<1, true, false, false, false, false><<<512, 256, 0, stream>>>(
      vw_bf, 0, Txln, (size_t)C * N, v_b, nullptr, nullptr,
      vt_bf, nullptr, N, C, N, N, 2, 3, 999);

  // att partials: q @ k^T  M=512,Nc=512, K=1024 split 2x512  grid 4x4x16x2
  gemm128<0, false, false, true, false, true><<<512, 256, 0, stream>>>(
      q_bf, (size_t)C * N, k_bf, (size_t)C * N, nullptr, nullptr, nullptr,
      att_raw, att_raw2, C, C, 512, N, 2, 2, 999);

  // softmax((p0+p1) * 1/32) -> att_bf
  softmax_kernel<<<B * C, 256, 0, stream>>>(att_raw, att_raw2, att_bf);

  // W_A normalized bf16 (overwrites bytes [0,32MiB): partials dead)
  wa_kernel<<<B * N * N / 4 / 256, 256, 0, stream>>>(adj, edge, dis, WA_bf);

  // Tx2[b,x,h] = Txln + att @ v   M=512,Nc=1024,K=512  grid 8x4x16
  gemm128<0, false, true, false, false, false><<<512, 256, 0, stream>>>(
      att_bf, (size_t)C * C, vt_bf, (size_t)N * C, nullptr, nullptr, Txln,
      Tx2_bf, nullptr, C, N, C, C, 3, 2, 999);

  // X3[b,n,o] = W_A @ X2   M=1024,Nc=512,K=1024  grid 4x8x16
  gemm128<0, false, false, false, false, false><<<512, 256, 0, stream>>>(
      WA_bf, (size_t)N * N, Tx2_bf, (size_t)C * N, nullptr, nullptr, nullptr,
      X3_bf, nullptr, N, C, N, N, 2, 3, 999);

  // final LN over o (D=512) -> f32 out   (128 thr x VPT4, 8B/lane loads)
  ln_kernel<4, 2, true><<<B * N, 128, 0, stream>>>(X3_bf, n2w, n2b, out, C);
}